// Round 10
// baseline (612.282 us; speedup 1.0000x reference)
//
#include <hip/hip_runtime.h>
#include <hip/hip_bf16.h>
#include <math.h>

// ConformerBlock on MI355X. B=4, S=4096, D=512, H=8, Hd=64, CTX=128, FFN=2048, KS=31.
// fp32 inputs/outputs. bf16 MFMA GEMMs, fused QKV, MFMA flash attention, tiled
// depthwise conv. Residual fp32 in ws.
// R1: cheap sigmoid-form GELU, padded transpose buffer (stride 36).
// R2: 2-phase pipeline in k_gemm (double-buffered LDS, 1 barrier/K-step).
// R3: k_attn: Q frags in registers, reg-staged K/V prefetch, Pb barrier removed.
// R4: k_attn: -INF-padded bias table, defer-max fast path, setprio MFMA.
// R5/R6: counted-vmcnt DEPTH=3 — regression. Reverted.
// R7: TM=64 tile — regression (FETCH +35%). Reverted.
// R8: 8-wave MODE2 GEMM — no gain => GEMM not TLP-bound. Reverted.
// R9: all GEMMs on 128x128 / 4-wave / 64x64-wave-tile (2.0 MFMA/ds_read). [598us]
// R10: k_attn is VALU-latency-bound (VALU 39% busy, idle 60%, 16 waves/CU).
//      Same 128-row block as 8 waves x 16 q-rows (512 thr), launch_bounds(512,6)
//      -> 24 waves/CU (+50% TLP). Identical math/traffic/sync; LDS unchanged.

using bf16 = __hip_bfloat16;
typedef __bf16 bf16x8_t __attribute__((ext_vector_type(8)));
typedef float f32x4_t __attribute__((ext_vector_type(4)));

static __device__ __forceinline__ float bf2f(bf16 v) { return __bfloat162float(v); }
static __device__ __forceinline__ bf16 f2bf(float v) { return __float2bfloat16(v); }

#define GLOAD_LDS16(g, l)                                                            \
    __builtin_amdgcn_global_load_lds((const __attribute__((address_space(1))) void*)(g), \
                                     (__attribute__((address_space(3))) void*)(l), 16, 0, 0)

// ---------------- fused weight conversion: fp32 [K][N] -> bf16 [N][K] (10 matrices) ----
struct WSrcs { const float* s[10]; };
__global__ __launch_bounds__(256) void k_wconv(WSrcs srcs, bf16* __restrict__ wc) {
    // segment tables (block counts per matrix; 32x32 tiles)
    const int start[11] = {0, 1024, 2048, 3072, 4096, 4352, 4608, 4864, 5120, 5632, 5888};
    const int Ks[10]    = {512, 2048, 512, 2048, 512, 512, 512, 512, 512, 512};
    const int Ns[10]    = {2048, 512, 2048, 512, 512, 512, 512, 512, 1024, 512};
    const int doff[10]  = {0, 1048576, 2097152, 3145728, 4194304, 4456448, 4718592, 4980736, 5242880, 5767168};
    int id = blockIdx.x, seg = 0;
#pragma unroll
    for (int i = 1; i < 10; ++i) seg += (id >= start[i]);
    int lid = id - start[seg];
    int K = Ks[seg], N = Ns[seg];
    int nbx = N >> 5;
    int bx = lid % nbx, by = lid / nbx;
    int nb = bx * 32, kb = by * 32;
    const float* in = srcs.s[seg];
    bf16* out = wc + doff[seg];
    bool inter = (seg == 8);
    __shared__ float t[32][33];
    int c = threadIdx.x & 31, r0 = threadIdx.x >> 5;
#pragma unroll
    for (int i = 0; i < 4; ++i)
        t[r0 + i * 8][c] = in[(size_t)(kb + r0 + i * 8) * N + nb + c];
    __syncthreads();
#pragma unroll
    for (int i = 0; i < 4; ++i) {
        int n = nb + r0 + i * 8;
        int orow = inter ? ((n < 512) ? 2 * n : 2 * (n - 512) + 1) : n;
        out[(size_t)orow * K + kb + c] = f2bf(t[c][r0 + i * 8]);
    }
}

// ---------------- LayerNorm: 256 thr / 4 rows, one wave per row of 512 ----------------
template <bool BF16OUT>
__global__ __launch_bounds__(256) void k_ln(const float* __restrict__ x, const float* __restrict__ g,
                                            const float* __restrict__ b, void* __restrict__ outp) {
    int row = blockIdx.x * 4 + (threadIdx.x >> 6), t = threadIdx.x & 63;
    const float* xr = x + (size_t)row * 512 + t * 8;
    float4 v0 = *(const float4*)xr;
    float4 v1 = *(const float4*)(xr + 4);
    float vals[8] = {v0.x, v0.y, v0.z, v0.w, v1.x, v1.y, v1.z, v1.w};
    float s = 0.f, ss = 0.f;
#pragma unroll
    for (int j = 0; j < 8; ++j) { s += vals[j]; ss += vals[j] * vals[j]; }
#pragma unroll
    for (int o = 32; o > 0; o >>= 1) { s += __shfl_xor(s, o, 64); ss += __shfl_xor(ss, o, 64); }
    float mean = s * (1.0f / 512.0f);
    float var  = ss * (1.0f / 512.0f) - mean * mean;
    float r = rsqrtf(var + 1e-5f);
    float4 g0 = *(const float4*)(g + t * 8);
    float4 g1 = *(const float4*)(g + t * 8 + 4);
    float4 b0 = *(const float4*)(b + t * 8);
    float4 b1 = *(const float4*)(b + t * 8 + 4);
    float gv[8] = {g0.x, g0.y, g0.z, g0.w, g1.x, g1.y, g1.z, g1.w};
    float bv[8] = {b0.x, b0.y, b0.z, b0.w, b1.x, b1.y, b1.z, b1.w};
    float ov[8];
#pragma unroll
    for (int j = 0; j < 8; ++j) ov[j] = (vals[j] - mean) * r * gv[j] + bv[j];
    if (BF16OUT) {
        union { uint4 u; bf16 h[8]; } oo;
#pragma unroll
        for (int j = 0; j < 8; ++j) oo.h[j] = f2bf(ov[j]);
        *(uint4*)((bf16*)outp + (size_t)row * 512 + t * 8) = oo.u;
    } else {
        float* op = (float*)outp + (size_t)row * 512 + t * 8;
        *(float4*)op = make_float4(ov[0], ov[1], ov[2], ov[3]);
        *(float4*)(op + 4) = make_float4(ov[4], ov[5], ov[6], ov[7]);
    }
}

// ---------------- GEMM: C = A[M,K] @ Bt[N,K]^T + bias, 128x128 tile, XCD swizzle --------
// MODE 0: bf16 store. MODE 1: fast GELU -> bf16. MODE 2: fp32 out = resid + scale*(acc+bias).
// MODE 3: QKV scatter. MODE 5: fused GLU (interleaved a/gate cols) -> bf16 [M][N/2].
// 2-phase double-buffered pipeline: one __syncthreads per K-step, next K-tile's
// global_load_lds issued before current tile's MFMA. 4 waves as 2x2 of 64x64 —
// 16 MFMA per 8 ds_read_b128 per wave per step (best MFMA/LDS ratio of this family).
// Epilogue: per-wave padded LDS transpose (stride 36 floats) aliased on smem.
template <int MODE, int TN>
__global__ __launch_bounds__(256) void k_gemm(const bf16* __restrict__ A, const bf16* __restrict__ Bt,
                                              const float* __restrict__ bias, void* __restrict__ outp,
                                              int M, int N, int K, float scale,
                                              const float* __restrict__ b2, const float* __restrict__ b3,
                                              const float* __restrict__ resid, int nbx) {
    constexpr int TM = 128;
    constexpr int NT = TN / 32;                 // B frags per wave
    __shared__ __align__(16) bf16 sm[2][(TM + TN) * 32];
    int id = blockIdx.x;
    int xcd = id & 7, slot = id >> 3;
    int nbyg = (gridDim.x / nbx) >> 3;
    int bxi = slot % nbx;
    int byi = slot / nbx + xcd * nbyg;
    int bn = bxi * TN, bm = byi * TM;
    int tid = threadIdx.x, w = tid >> 6, l = tid & 63;
    int l15 = l & 15, quad = l >> 4;
    int wm = (w >> 1) * 64, wn = (w & 1) * (TN / 2);
    f32x4_t acc[4][NT] = {};
    const int brows = TN / 4;
    const bf16* ag = A + (size_t)(bm + w * 32 + (l >> 2)) * K + (l & 3) * 8;
    const bf16* bg = Bt + (size_t)(bn + w * brows + (l >> 2)) * K + (l & 3) * 8;

    // stage K-tile k0 into buffer `buf` (async; drained by the next __syncthreads)
    auto stage = [&](int buf, int k0) {
        bf16* asl = sm[buf] + w * 32 * 32;
        bf16* bsl = sm[buf] + TM * 32 + w * brows * 32;
#pragma unroll
        for (int j = 0; j < 2; ++j)
            GLOAD_LDS16(ag + (size_t)j * 16 * K + k0, asl + j * 16 * 32);
#pragma unroll
        for (int j = 0; j < TN / 64; ++j)
            GLOAD_LDS16(bg + (size_t)j * 16 * K + k0, bsl + j * 16 * 32);
    };
    auto compute = [&](int buf) {
        bf16x8_t af[4], bfr[NT];
#pragma unroll
        for (int tm = 0; tm < 4; ++tm)
            af[tm] = *(const bf16x8_t*)(sm[buf] + (wm + tm * 16 + l15) * 32 + quad * 8);
#pragma unroll
        for (int tn = 0; tn < NT; ++tn)
            bfr[tn] = *(const bf16x8_t*)(sm[buf] + TM * 32 + (wn + tn * 16 + l15) * 32 + quad * 8);
#pragma unroll
        for (int tm = 0; tm < 4; ++tm)
#pragma unroll
            for (int tn = 0; tn < NT; ++tn)
                acc[tm][tn] = __builtin_amdgcn_mfma_f32_16x16x32_bf16(af[tm], bfr[tn], acc[tm][tn], 0, 0, 0);
    };

    const int nt = K >> 5;
    stage(0, 0);
    int cur = 0;
    for (int t = 0; t < nt; ++t) {
        __syncthreads();                         // buf[cur] ready (own vmcnt(0) drained)
        if (t + 1 < nt) stage(cur ^ 1, (t + 1) * 32);   // prefetch: lands during compute
        compute(cur);
        cur ^= 1;
    }
    // -------- coalesced epilogue via per-wave padded LDS transpose (aliased on smem) --------
    __syncthreads();                             // last frag reads done before overlay reuse
    float* tb = (float*)(&sm[0][0]) + w * 576;   // 16 rows x 36 floats per wave (9216B)
#pragma unroll
    for (int tm = 0; tm < 4; ++tm)
#pragma unroll
        for (int cp = 0; cp < NT / 2; ++cp) {
#pragma unroll
            for (int j = 0; j < 2; ++j)
#pragma unroll
                for (int r = 0; r < 4; ++r)
                    tb[(quad * 4 + r) * 36 + j * 16 + l15] = acc[tm][2 * cp + j][r];
            // read back row-major: lane -> row l>>2, cols (l&3)*8 .. +8
            int lr = l >> 2, lc = (l & 3) * 8;
            float v[8];
#pragma unroll
            for (int i = 0; i < 8; ++i) v[i] = tb[lr * 36 + lc + i];
            int gr = bm + wm + tm * 16 + lr;
            int gc = bn + wn + cp * 32 + lc;
            if (MODE == 0 || MODE == 1) {
                union { uint4 u; bf16 h[8]; } oo;
#pragma unroll
                for (int i = 0; i < 8; ++i) {
                    float vv = v[i] + bias[gc + i];
                    if (MODE == 1) {
                        // sigmoid-form tanh-GELU: x*sigmoid(1.5957691*(x+0.044715*x^3))
                        // max |err| vs exact erf-GELU ~5e-4, far below bf16 output quantum
                        float z = vv * (1.5957691f + 0.07135481f * vv * vv);
                        vv = vv / (1.f + __expf(-z));
                    }
                    oo.h[i] = f2bf(vv);
                }
                *(uint4*)((bf16*)outp + (size_t)gr * N + gc) = oo.u;
            } else if (MODE == 2) {
                size_t ix = (size_t)gr * N + gc;
                float4 r0 = *(const float4*)(resid + ix);
                float4 r1 = *(const float4*)(resid + ix + 4);
                float rr[8] = {r0.x, r0.y, r0.z, r0.w, r1.x, r1.y, r1.z, r1.w};
                float o[8];
#pragma unroll
                for (int i = 0; i < 8; ++i) o[i] = rr[i] + scale * (v[i] + bias[gc + i]);
                *(float4*)((float*)outp + ix) = make_float4(o[0], o[1], o[2], o[3]);
                *(float4*)((float*)outp + ix + 4) = make_float4(o[4], o[5], o[6], o[7]);
            } else if (MODE == 3) {
                const float* bp = (gc < 512) ? bias : (gc < 1024 ? b2 : b3);
                int cc = gc & 511;
                union { uint4 u; bf16 h[8]; } oo;
#pragma unroll
                for (int i = 0; i < 8; ++i) oo.h[i] = f2bf(v[i] + bp[cc + i]);
                bf16* ob = (bf16*)outp + (size_t)(gc >> 9) * 8388608;
                *(uint4*)(ob + (size_t)gr * 512 + cc) = oo.u;
            } else {                             // MODE 5: GLU, interleaved pairs in-lane
                union { ushort4 u; bf16 h[4]; } oo;
#pragma unroll
                for (int p = 0; p < 4; ++p) {
                    int ic = gc + 2 * p;         // even: a (orig col ic/2), odd: gate (+512)
                    float a = v[2 * p] + bias[ic >> 1];
                    float gt = v[2 * p + 1] + bias[(ic >> 1) + 512];
                    oo.h[p] = f2bf(a / (1.f + __expf(-gt)));
                }
                *(ushort4*)((bf16*)outp + (size_t)gr * (N >> 1) + (gc >> 1)) = oo.u;
            }
        }
}

// ---------------- MFMA flash attention over 384-key windows ----------------
// R10: 512 threads / 8 waves, 16 q-rows per wave (was 4 waves x 32 rows).
// Q fragments in registers (pre-scaled 1/8). K/V reg-staged with prefetch (one uint4
// each per thread). Pb wave-local [8][16][72]. -INF-padded bias table, defer-max,
// setprio MFMA. Same 2 barriers/chunk; identical math to R4-R9 version.
__global__ __launch_bounds__(512, 6) void k_attn(const bf16* __restrict__ q, const bf16* __restrict__ k,
                                                 const bf16* __restrict__ v, const float* __restrict__ rel_bias,
                                                 bf16* __restrict__ out) {
    __shared__ __align__(16) bf16 Ks[64][72];
    __shared__ __align__(16) bf16 Vt[64][72];
    __shared__ __align__(16) bf16 Pb[8][16][72];
    __shared__ float relb2[512];                 // idx = rel + 255; -INF outside |rel|<=128
    int blk = blockIdx.x;
    int n = blk & 31, h = (blk >> 5) & 7, b = blk >> 8;
    int tid = threadIdx.x, w = tid >> 6, lane = tid & 63;
    int l15 = lane & 15, quad = lane >> 4;
    {
        int rel = tid - 255;                     // 512 threads cover the 512-entry table
        relb2[tid] = (rel >= -128 && rel <= 128) ? rel_bias[h * 257 + rel + 128] : -INFINITY;
    }
    // Q fragments in registers, scaled by 0.125 (exact power-of-2 in bf16)
    bf16x8_t qf[2];
#pragma unroll
    for (int ks = 0; ks < 2; ++ks) {
        const bf16* qg = q + (size_t)(b * 4096 + n * 128 + w * 16 + l15) * 512
                           + h * 64 + ks * 32 + quad * 8;
        bf16x8_t f = *(const bf16x8_t*)qg;
#pragma unroll
        for (int j = 0; j < 8; ++j) f[j] = (__bf16)(0.125f * (float)f[j]);
        qf[ks] = f;
    }
    float m_run[4], l_run[4];
#pragma unroll
    for (int r = 0; r < 4; ++r) { m_run[r] = -1e30f; l_run[r] = 0.f; }
    f32x4_t Oacc[4] = {};
    int kv0 = n * 128 - 128;
    int lo = (n == 0) ? 2 : 0;
    int hi = (n == 31) ? 4 : 6;
    int tbase = l15 + 127 - w * 16 - quad * 4;   // bias-table base (per-thread, hoisted)
    // K/V register staging: one uint4 each per thread (512 thr x 16B = 8KB per tensor)
    int krow = tid >> 3, kcol = (tid & 7) * 8;
    uint4 kr;
    union { uint4 u; bf16 hh[8]; } vr;
    auto loadKV = [&](int kst) {
        kr = *(const uint4*)(k + (size_t)(b * 4096 + kst + krow) * 512 + h * 64 + kcol);
        vr.u = *(const uint4*)(v + (size_t)(b * 4096 + kst + krow) * 512 + h * 64 + kcol);
    };
    loadKV(kv0 + lo * 64);
    for (int ch = lo; ch < hi; ++ch) {
        __syncthreads();                         // prev chunk's MFMA reads of Ks/Vt done
        *(uint4*)&Ks[krow][kcol] = kr;
#pragma unroll
        for (int j = 0; j < 8; ++j) Vt[kcol + j][krow] = vr.hh[j];
        if (ch + 1 < hi) loadKV(kv0 + (ch + 1) * 64);   // prefetch: lands during compute
        __syncthreads();
        float sc[4][4];
        __builtin_amdgcn_s_setprio(1);
#pragma unroll
        for (int nt = 0; nt < 4; ++nt) {
            f32x4_t a = {};
#pragma unroll
            for (int ks = 0; ks < 2; ++ks) {
                bf16x8_t kf = *(const bf16x8_t*)&Ks[nt * 16 + l15][ks * 32 + quad * 8];
                a = __builtin_amdgcn_mfma_f32_16x16x32_bf16(qf[ks], kf, a, 0, 0, 0);
            }
#pragma unroll
            for (int r = 0; r < 4; ++r) sc[nt][r] = a[r];
        }
        __builtin_amdgcn_s_setprio(0);
        // bias + mask via padded table: one LDS read + one add per element
        {
            int tb0 = tbase + ch * 64;
#pragma unroll
            for (int nt = 0; nt < 4; ++nt)
#pragma unroll
                for (int r = 0; r < 4; ++r)
                    sc[nt][r] += relb2[tb0 + nt * 16 - r];
        }
        // row max + defer-max decision (THR=8, wave-uniform)
        float mx[4];
        int need = 0;
#pragma unroll
        for (int r = 0; r < 4; ++r) {
            float m3 = fmaxf(fmaxf(sc[0][r], sc[1][r]), fmaxf(sc[2][r], sc[3][r]));
#pragma unroll
            for (int mk = 1; mk <= 8; mk <<= 1) m3 = fmaxf(m3, __shfl_xor(m3, mk, 64));
            mx[r] = m3;
            need |= (m3 > m_run[r] + 8.f) ? 1 : 0;
        }
        bool slow = __any(need);
        float al[4];
#pragma unroll
        for (int r = 0; r < 4; ++r) {
            float mn = slow ? fmaxf(m_run[r], mx[r]) : m_run[r];
            float ps = 0.f;
#pragma unroll
            for (int nt = 0; nt < 4; ++nt) {
                float p = __expf(sc[nt][r] - mn);
                sc[nt][r] = p;
                ps += p;
            }
#pragma unroll
            for (int mk = 1; mk <= 8; mk <<= 1) ps += __shfl_xor(ps, mk, 64);
            if (slow) {
                float a = __expf(m_run[r] - mn);
                l_run[r] = l_run[r] * a + ps;
                m_run[r] = mn;
                al[r] = a;
            } else {
                l_run[r] += ps;
            }
        }
        // P -> LDS (wave-local buffer; same-wave read below needs no barrier)
#pragma unroll
        for (int nt = 0; nt < 4; ++nt)
#pragma unroll
            for (int r = 0; r < 4; ++r)
                Pb[w][quad * 4 + r][nt * 16 + l15] = f2bf(sc[nt][r]);
        if (slow) {
#pragma unroll
            for (int dt = 0; dt < 4; ++dt)
#pragma unroll
                for (int r = 0; r < 4; ++r)
                    Oacc[dt][r] *= al[r];
        }
        bf16x8_t pf[2];
#pragma unroll
        for (int ks = 0; ks < 2; ++ks)
            pf[ks] = *(const bf16x8_t*)&Pb[w][l15][ks * 32 + quad * 8];
        __builtin_amdgcn_s_setprio(1);
#pragma unroll
        for (int dt = 0; dt < 4; ++dt) {
            f32x4_t a = Oacc[dt];
#pragma unroll
            for (int ks = 0; ks < 2; ++ks) {
                bf16x8_t vf = *(const bf16x8_t*)&Vt[dt * 16 + l15][ks * 32 + quad * 8];
                a = __builtin_amdgcn_mfma_f32_16x16x32_bf16(pf[ks], vf, a, 0, 0, 0);
            }
            Oacc[dt] = a;
        }
        __builtin_amdgcn_s_setprio(0);
    }
#pragma unroll
    for (int r = 0; r < 4; ++r) {
        float inv = 1.f / l_run[r];
        int row = n * 128 + w * 16 + quad * 4 + r;
#pragma unroll
        for (int dt = 0; dt < 4; ++dt)
            out[(size_t)(b * 4096 + row) * 512 + h * 64 + dt * 16 + l15] = f2bf(Oacc[dt][r] * inv);
    }
}

// ---------------- tiled depthwise conv (KS=31) + BN + SiLU ----------------
__global__ __launch_bounds__(256) void k_conv(const bf16* __restrict__ in, const float* __restrict__ w,
                                              const float* __restrict__ wb, const float* __restrict__ bg,
                                              const float* __restrict__ bb2, const float* __restrict__ bm,
                                              const float* __restrict__ bvv, bf16* __restrict__ out) {
    __shared__ float wl[64 * 31];
    int d0 = blockIdx.x * 64, s0 = blockIdx.y * 64, b = blockIdx.z;
    for (int i = threadIdx.x; i < 64 * 31; i += 256) wl[i] = w[d0 * 31 + i];
    __syncthreads();
    int dl = threadIdx.x & 63, chunk = threadIdx.x >> 6;
    int d = d0 + dl;
    int s00 = s0 + chunk * 16;
    float wr[31];
#pragma unroll
    for (int t = 0; t < 31; ++t) wr[t] = wl[dl * 31 + t];
    float xw[46];
    const bf16* base = in + (size_t)(b * 4096) * 512 + d;
#pragma unroll
    for (int i = 0; i < 46; ++i) {
        int s = s00 - 15 + i;
        xw[i] = (s >= 0 && s < 4096) ? bf2f(base[(size_t)s * 512]) : 0.f;
    }
    float scv = bg[d] * rsqrtf(bvv[d] + 1e-5f);
    float wbd = wb[d], bmd = bm[d], bbd = bb2[d];
    bf16* op = out + (size_t)(b * 4096 + s00) * 512 + d;
#pragma unroll
    for (int j = 0; j < 16; ++j) {
        float acc = 0.f;
#pragma unroll
        for (int t = 0; t < 31; ++t) acc += wr[t] * xw[j + t];
        acc += wbd;
        acc = (acc - bmd) * scv + bbd;
        acc = acc / (1.f + __expf(-acc));
        op[(size_t)j * 512] = f2bf(acc);
    }
}

extern "C" void kernel_launch(void* const* d_in, const int* in_sizes, int n_in,
                              void* d_out, int out_size, void* d_ws, size_t ws_size,
                              hipStream_t stream) {
    (void)in_sizes; (void)n_in; (void)out_size; (void)ws_size;
    const float* x = (const float*)d_in[0];
    char* ws = (char*)d_ws;
    float* xf   = (float*)ws;                      // [0,32M)   fp32 residual
    bf16* ln_bf = (bf16*)(ws + 33554432);          // [32M,48M) LN output (bf16)
    bf16* h_bf  = (bf16*)(ws + 50331648);          // [48M,112M) hidden / q,k,v
    bf16* g_bf  = (bf16*)(ws + 117440512);         // [112M,128M) GLU out
    bf16* t_bf  = (bf16*)(ws + 134217728);         // [128M,144M) attn/conv out
    bf16* wc    = (bf16*)(ws + 150994944);         // [144M,...) converted bf16 weights
    bf16 *qb = h_bf;
    bf16* w_f11 = wc;                // [2048][512]
    bf16* w_f12 = wc + 1048576;      // [512][2048]
    bf16* w_f21 = wc + 2097152;      // [2048][512]
    bf16* w_f22 = wc + 3145728;      // [512][2048]
    bf16* w_q   = wc + 4194304;      // [1536][512] fused qkv (contiguous)
    bf16* w_o   = wc + 4980736;      // [512][512]
    bf16* w_p1  = wc + 5242880;      // [1024][512] interleaved a/gate rows
    bf16* w_p2  = wc + 5767168;      // [512][512]

    // fused weight conversion (10 matrices, one launch)
    WSrcs srcs;
    srcs.s[0] = (const float*)d_in[3];  srcs.s[1] = (const float*)d_in[5];
    srcs.s[2] = (const float*)d_in[9];  srcs.s[3] = (const float*)d_in[11];
    srcs.s[4] = (const float*)d_in[15]; srcs.s[5] = (const float*)d_in[16];
    srcs.s[6] = (const float*)d_in[17]; srcs.s[7] = (const float*)d_in[18];
    srcs.s[8] = (const float*)d_in[26]; srcs.s[9] = (const float*)d_in[34];
    k_wconv<<<5888, 256, 0, stream>>>(srcs, wc);

    // FFN1: xf = x + 0.5*FFN(LN(x))
    k_ln<true><<<4096, 256, 0, stream>>>(x, (const float*)d_in[1], (const float*)d_in[2], ln_bf);
    k_gemm<1, 128><<<2048, 256, 0, stream>>>(ln_bf, w_f11, (const float*)d_in[4], h_bf, 16384, 2048, 512, 0.f, nullptr, nullptr, nullptr, 16);
    k_gemm<2, 128><<<512, 256, 0, stream>>>(h_bf, w_f12, (const float*)d_in[6], xf, 16384, 512, 2048, 0.5f, nullptr, nullptr, x, 4);
    // attention (fused QKV)
    k_ln<true><<<4096, 256, 0, stream>>>(xf, (const float*)d_in[13], (const float*)d_in[14], ln_bf);
    k_gemm<3, 128><<<1536, 256, 0, stream>>>(ln_bf, w_q, (const float*)d_in[19], qb, 16384, 1536, 512, 0.f,
                                             (const float*)d_in[20], (const float*)d_in[21], nullptr, 12);
    k_attn<<<1024, 512, 0, stream>>>(qb, qb + 8388608, qb + 16777216, (const float*)d_in[23], t_bf);
    k_gemm<2, 128><<<512, 256, 0, stream>>>(t_bf, w_o, (const float*)d_in[22], xf, 16384, 512, 512, 1.0f, nullptr, nullptr, xf, 4);
    // conv module (pw1 + fused GLU)
    k_ln<true><<<4096, 256, 0, stream>>>(xf, (const float*)d_in[24], (const float*)d_in[25], ln_bf);
    k_gemm<5, 128><<<1024, 256, 0, stream>>>(ln_bf, w_p1, (const float*)d_in[27], g_bf, 16384, 1024, 512, 0.f, nullptr, nullptr, nullptr, 8);
    k_conv<<<dim3(8, 64, 4), 256, 0, stream>>>(g_bf, (const float*)d_in[28], (const float*)d_in[29], (const float*)d_in[30],
                                               (const float*)d_in[31], (const float*)d_in[32], (const float*)d_in[33], t_bf);
    k_gemm<2, 128><<<512, 256, 0, stream>>>(t_bf, w_p2, (const float*)d_in[35], xf, 16384, 512, 512, 1.0f, nullptr, nullptr, xf, 4);
    // FFN2
    k_ln<true><<<4096, 256, 0, stream>>>(xf, (const float*)d_in[7], (const float*)d_in[8], ln_bf);
    k_gemm<1, 128><<<2048, 256, 0, stream>>>(ln_bf, w_f21, (const float*)d_in[10], h_bf, 16384, 2048, 512, 0.f, nullptr, nullptr, nullptr, 16);
    k_gemm<2, 128><<<512, 256, 0, stream>>>(h_bf, w_f22, (const float*)d_in[12], xf, 16384, 512, 2048, 0.5f, nullptr, nullptr, xf, 4);
    // final LN -> fp32 out
    k_ln<false><<<4096, 256, 0, stream>>>(xf, (const float*)d_in[36], (const float*)d_in[37], d_out);
}

// Round 11
// 586.591 us; speedup vs baseline: 1.0438x; 1.0438x over previous
//
#include <hip/hip_runtime.h>
#include <hip/hip_bf16.h>
#include <math.h>

// ConformerBlock on MI355X. B=4, S=4096, D=512, H=8, Hd=64, CTX=128, FFN=2048, KS=31.
// fp32 inputs/outputs. bf16 MFMA GEMMs, fused QKV, MFMA flash attention, tiled
// depthwise conv. Residual fp32 in ws.
// R1: cheap sigmoid-form GELU, padded transpose buffer (stride 36).
// R2: 2-phase pipeline in k_gemm (double-buffered LDS, 1 barrier/K-step).
// R3: k_attn: Q frags in registers, reg-staged K/V prefetch, Pb barrier removed.
// R4: k_attn: -INF-padded bias table, defer-max fast path, setprio MFMA.
// R5/R6: counted-vmcnt DEPTH=3 — regression. Reverted.
// R7: TM=64 tile — regression (FETCH +35%). Reverted.
// R8: 8-wave MODE2 GEMM — no gain => GEMM not TLP-bound. Reverted.
// R9: all GEMMs on 128x128 / 4-wave / 64x64-wave-tile (2.0 MFMA/ds_read). [598us]
// R10: 8-wave attn — regression: FETCH 56->106MB, WRITE 16->89MB (L2 thrash from
//      doubled per-CU working set). Reverted to 4-wave R9 attn.
// R11: attn XCD-locality swizzle: blk remap (blk&7)*128 + (blk>>3) puts consecutive
//      query blocks n (whose 384-key windows overlap 2/3) on the SAME XCD ->
//      window reuse hits private L2 instead of re-fetching HBM. Bijective (1024=8x128).

using bf16 = __hip_bfloat16;
typedef __bf16 bf16x8_t __attribute__((ext_vector_type(8)));
typedef float f32x4_t __attribute__((ext_vector_type(4)));

static __device__ __forceinline__ float bf2f(bf16 v) { return __bfloat162float(v); }
static __device__ __forceinline__ bf16 f2bf(float v) { return __float2bfloat16(v); }

#define GLOAD_LDS16(g, l)                                                            \
    __builtin_amdgcn_global_load_lds((const __attribute__((address_space(1))) void*)(g), \
                                     (__attribute__((address_space(3))) void*)(l), 16, 0, 0)

// ---------------- fused weight conversion: fp32 [K][N] -> bf16 [N][K] (10 matrices) ----
struct WSrcs { const float* s[10]; };
__global__ __launch_bounds__(256) void k_wconv(WSrcs srcs, bf16* __restrict__ wc) {
    // segment tables (block counts per matrix; 32x32 tiles)
    const int start[11] = {0, 1024, 2048, 3072, 4096, 4352, 4608, 4864, 5120, 5632, 5888};
    const int Ks[10]    = {512, 2048, 512, 2048, 512, 512, 512, 512, 512, 512};
    const int Ns[10]    = {2048, 512, 2048, 512, 512, 512, 512, 512, 1024, 512};
    const int doff[10]  = {0, 1048576, 2097152, 3145728, 4194304, 4456448, 4718592, 4980736, 5242880, 5767168};
    int id = blockIdx.x, seg = 0;
#pragma unroll
    for (int i = 1; i < 10; ++i) seg += (id >= start[i]);
    int lid = id - start[seg];
    int K = Ks[seg], N = Ns[seg];
    int nbx = N >> 5;
    int bx = lid % nbx, by = lid / nbx;
    int nb = bx * 32, kb = by * 32;
    const float* in = srcs.s[seg];
    bf16* out = wc + doff[seg];
    bool inter = (seg == 8);
    __shared__ float t[32][33];
    int c = threadIdx.x & 31, r0 = threadIdx.x >> 5;
#pragma unroll
    for (int i = 0; i < 4; ++i)
        t[r0 + i * 8][c] = in[(size_t)(kb + r0 + i * 8) * N + nb + c];
    __syncthreads();
#pragma unroll
    for (int i = 0; i < 4; ++i) {
        int n = nb + r0 + i * 8;
        int orow = inter ? ((n < 512) ? 2 * n : 2 * (n - 512) + 1) : n;
        out[(size_t)orow * K + kb + c] = f2bf(t[c][r0 + i * 8]);
    }
}

// ---------------- LayerNorm: 256 thr / 4 rows, one wave per row of 512 ----------------
template <bool BF16OUT>
__global__ __launch_bounds__(256) void k_ln(const float* __restrict__ x, const float* __restrict__ g,
                                            const float* __restrict__ b, void* __restrict__ outp) {
    int row = blockIdx.x * 4 + (threadIdx.x >> 6), t = threadIdx.x & 63;
    const float* xr = x + (size_t)row * 512 + t * 8;
    float4 v0 = *(const float4*)xr;
    float4 v1 = *(const float4*)(xr + 4);
    float vals[8] = {v0.x, v0.y, v0.z, v0.w, v1.x, v1.y, v1.z, v1.w};
    float s = 0.f, ss = 0.f;
#pragma unroll
    for (int j = 0; j < 8; ++j) { s += vals[j]; ss += vals[j] * vals[j]; }
#pragma unroll
    for (int o = 32; o > 0; o >>= 1) { s += __shfl_xor(s, o, 64); ss += __shfl_xor(ss, o, 64); }
    float mean = s * (1.0f / 512.0f);
    float var  = ss * (1.0f / 512.0f) - mean * mean;
    float r = rsqrtf(var + 1e-5f);
    float4 g0 = *(const float4*)(g + t * 8);
    float4 g1 = *(const float4*)(g + t * 8 + 4);
    float4 b0 = *(const float4*)(b + t * 8);
    float4 b1 = *(const float4*)(b + t * 8 + 4);
    float gv[8] = {g0.x, g0.y, g0.z, g0.w, g1.x, g1.y, g1.z, g1.w};
    float bv[8] = {b0.x, b0.y, b0.z, b0.w, b1.x, b1.y, b1.z, b1.w};
    float ov[8];
#pragma unroll
    for (int j = 0; j < 8; ++j) ov[j] = (vals[j] - mean) * r * gv[j] + bv[j];
    if (BF16OUT) {
        union { uint4 u; bf16 h[8]; } oo;
#pragma unroll
        for (int j = 0; j < 8; ++j) oo.h[j] = f2bf(ov[j]);
        *(uint4*)((bf16*)outp + (size_t)row * 512 + t * 8) = oo.u;
    } else {
        float* op = (float*)outp + (size_t)row * 512 + t * 8;
        *(float4*)op = make_float4(ov[0], ov[1], ov[2], ov[3]);
        *(float4*)(op + 4) = make_float4(ov[4], ov[5], ov[6], ov[7]);
    }
}

// ---------------- GEMM: C = A[M,K] @ Bt[N,K]^T + bias, 128x128 tile, XCD swizzle --------
// MODE 0: bf16 store. MODE 1: fast GELU -> bf16. MODE 2: fp32 out = resid + scale*(acc+bias).
// MODE 3: QKV scatter. MODE 5: fused GLU (interleaved a/gate cols) -> bf16 [M][N/2].
// 2-phase double-buffered pipeline: one __syncthreads per K-step, next K-tile's
// global_load_lds issued before current tile's MFMA. 4 waves as 2x2 of 64x64 —
// 16 MFMA per 8 ds_read_b128 per wave per step (best MFMA/LDS ratio of this family).
// Epilogue: per-wave padded LDS transpose (stride 36 floats) aliased on smem.
template <int MODE, int TN>
__global__ __launch_bounds__(256) void k_gemm(const bf16* __restrict__ A, const bf16* __restrict__ Bt,
                                              const float* __restrict__ bias, void* __restrict__ outp,
                                              int M, int N, int K, float scale,
                                              const float* __restrict__ b2, const float* __restrict__ b3,
                                              const float* __restrict__ resid, int nbx) {
    constexpr int TM = 128;
    constexpr int NT = TN / 32;                 // B frags per wave
    __shared__ __align__(16) bf16 sm[2][(TM + TN) * 32];
    int id = blockIdx.x;
    int xcd = id & 7, slot = id >> 3;
    int nbyg = (gridDim.x / nbx) >> 3;
    int bxi = slot % nbx;
    int byi = slot / nbx + xcd * nbyg;
    int bn = bxi * TN, bm = byi * TM;
    int tid = threadIdx.x, w = tid >> 6, l = tid & 63;
    int l15 = l & 15, quad = l >> 4;
    int wm = (w >> 1) * 64, wn = (w & 1) * (TN / 2);
    f32x4_t acc[4][NT] = {};
    const int brows = TN / 4;
    const bf16* ag = A + (size_t)(bm + w * 32 + (l >> 2)) * K + (l & 3) * 8;
    const bf16* bg = Bt + (size_t)(bn + w * brows + (l >> 2)) * K + (l & 3) * 8;

    // stage K-tile k0 into buffer `buf` (async; drained by the next __syncthreads)
    auto stage = [&](int buf, int k0) {
        bf16* asl = sm[buf] + w * 32 * 32;
        bf16* bsl = sm[buf] + TM * 32 + w * brows * 32;
#pragma unroll
        for (int j = 0; j < 2; ++j)
            GLOAD_LDS16(ag + (size_t)j * 16 * K + k0, asl + j * 16 * 32);
#pragma unroll
        for (int j = 0; j < TN / 64; ++j)
            GLOAD_LDS16(bg + (size_t)j * 16 * K + k0, bsl + j * 16 * 32);
    };
    auto compute = [&](int buf) {
        bf16x8_t af[4], bfr[NT];
#pragma unroll
        for (int tm = 0; tm < 4; ++tm)
            af[tm] = *(const bf16x8_t*)(sm[buf] + (wm + tm * 16 + l15) * 32 + quad * 8);
#pragma unroll
        for (int tn = 0; tn < NT; ++tn)
            bfr[tn] = *(const bf16x8_t*)(sm[buf] + TM * 32 + (wn + tn * 16 + l15) * 32 + quad * 8);
#pragma unroll
        for (int tm = 0; tm < 4; ++tm)
#pragma unroll
            for (int tn = 0; tn < NT; ++tn)
                acc[tm][tn] = __builtin_amdgcn_mfma_f32_16x16x32_bf16(af[tm], bfr[tn], acc[tm][tn], 0, 0, 0);
    };

    const int nt = K >> 5;
    stage(0, 0);
    int cur = 0;
    for (int t = 0; t < nt; ++t) {
        __syncthreads();                         // buf[cur] ready (own vmcnt(0) drained)
        if (t + 1 < nt) stage(cur ^ 1, (t + 1) * 32);   // prefetch: lands during compute
        compute(cur);
        cur ^= 1;
    }
    // -------- coalesced epilogue via per-wave padded LDS transpose (aliased on smem) --------
    __syncthreads();                             // last frag reads done before overlay reuse
    float* tb = (float*)(&sm[0][0]) + w * 576;   // 16 rows x 36 floats per wave (9216B)
#pragma unroll
    for (int tm = 0; tm < 4; ++tm)
#pragma unroll
        for (int cp = 0; cp < NT / 2; ++cp) {
#pragma unroll
            for (int j = 0; j < 2; ++j)
#pragma unroll
                for (int r = 0; r < 4; ++r)
                    tb[(quad * 4 + r) * 36 + j * 16 + l15] = acc[tm][2 * cp + j][r];
            // read back row-major: lane -> row l>>2, cols (l&3)*8 .. +8
            int lr = l >> 2, lc = (l & 3) * 8;
            float v[8];
#pragma unroll
            for (int i = 0; i < 8; ++i) v[i] = tb[lr * 36 + lc + i];
            int gr = bm + wm + tm * 16 + lr;
            int gc = bn + wn + cp * 32 + lc;
            if (MODE == 0 || MODE == 1) {
                union { uint4 u; bf16 h[8]; } oo;
#pragma unroll
                for (int i = 0; i < 8; ++i) {
                    float vv = v[i] + bias[gc + i];
                    if (MODE == 1) {
                        // sigmoid-form tanh-GELU: x*sigmoid(1.5957691*(x+0.044715*x^3))
                        // max |err| vs exact erf-GELU ~5e-4, far below bf16 output quantum
                        float z = vv * (1.5957691f + 0.07135481f * vv * vv);
                        vv = vv / (1.f + __expf(-z));
                    }
                    oo.h[i] = f2bf(vv);
                }
                *(uint4*)((bf16*)outp + (size_t)gr * N + gc) = oo.u;
            } else if (MODE == 2) {
                size_t ix = (size_t)gr * N + gc;
                float4 r0 = *(const float4*)(resid + ix);
                float4 r1 = *(const float4*)(resid + ix + 4);
                float rr[8] = {r0.x, r0.y, r0.z, r0.w, r1.x, r1.y, r1.z, r1.w};
                float o[8];
#pragma unroll
                for (int i = 0; i < 8; ++i) o[i] = rr[i] + scale * (v[i] + bias[gc + i]);
                *(float4*)((float*)outp + ix) = make_float4(o[0], o[1], o[2], o[3]);
                *(float4*)((float*)outp + ix + 4) = make_float4(o[4], o[5], o[6], o[7]);
            } else if (MODE == 3) {
                const float* bp = (gc < 512) ? bias : (gc < 1024 ? b2 : b3);
                int cc = gc & 511;
                union { uint4 u; bf16 h[8]; } oo;
#pragma unroll
                for (int i = 0; i < 8; ++i) oo.h[i] = f2bf(v[i] + bp[cc + i]);
                bf16* ob = (bf16*)outp + (size_t)(gc >> 9) * 8388608;
                *(uint4*)(ob + (size_t)gr * 512 + cc) = oo.u;
            } else {                             // MODE 5: GLU, interleaved pairs in-lane
                union { ushort4 u; bf16 h[4]; } oo;
#pragma unroll
                for (int p = 0; p < 4; ++p) {
                    int ic = gc + 2 * p;         // even: a (orig col ic/2), odd: gate (+512)
                    float a = v[2 * p] + bias[ic >> 1];
                    float gt = v[2 * p + 1] + bias[(ic >> 1) + 512];
                    oo.h[p] = f2bf(a / (1.f + __expf(-gt)));
                }
                *(ushort4*)((bf16*)outp + (size_t)gr * (N >> 1) + (gc >> 1)) = oo.u;
            }
        }
}

// ---------------- MFMA flash attention over 384-key windows ----------------
// 256 thr / 4 waves (R9-proven). Q fragments in registers (pre-scaled 1/8). K/V
// reg-staged with prefetch. Pb wave-local. -INF-padded bias table, defer-max,
// setprio MFMA. R11: XCD-locality block remap — consecutive n (overlapping K/V
// windows) land on the same XCD's L2. Bijective: 1024 = 8 * 128.
__global__ __launch_bounds__(256) void k_attn(const bf16* __restrict__ q, const bf16* __restrict__ k,
                                              const bf16* __restrict__ v, const float* __restrict__ rel_bias,
                                              bf16* __restrict__ out) {
    __shared__ __align__(16) bf16 Ks[64][72];
    __shared__ __align__(16) bf16 Vt[64][72];
    __shared__ __align__(16) bf16 Pb[4][32][72];
    __shared__ float relb2[512];                 // idx = rel + 255; -INF outside |rel|<=128
    int blk = blockIdx.x;
    blk = (blk & 7) * 128 + (blk >> 3);          // XCD x owns a contiguous run of (n,h)
    int n = blk & 31, h = (blk >> 5) & 7, b = blk >> 8;
    int tid = threadIdx.x, w = tid >> 6, lane = tid & 63;
    int l15 = lane & 15, quad = lane >> 4;
    for (int i = tid; i < 512; i += 256) {
        int rel = i - 255;
        relb2[i] = (rel >= -128 && rel <= 128) ? rel_bias[h * 257 + rel + 128] : -INFINITY;
    }
    // Q fragments in registers, scaled by 0.125 (exact power-of-2 in bf16)
    bf16x8_t qf[2][2];
#pragma unroll
    for (int qt = 0; qt < 2; ++qt)
#pragma unroll
        for (int ks = 0; ks < 2; ++ks) {
            const bf16* qg = q + (size_t)(b * 4096 + n * 128 + w * 32 + qt * 16 + l15) * 512
                               + h * 64 + ks * 32 + quad * 8;
            bf16x8_t f = *(const bf16x8_t*)qg;
#pragma unroll
            for (int j = 0; j < 8; ++j) f[j] = (__bf16)(0.125f * (float)f[j]);
            qf[qt][ks] = f;
        }
    float m_run[2][4], l_run[2][4];
#pragma unroll
    for (int qt = 0; qt < 2; ++qt)
#pragma unroll
        for (int r = 0; r < 4; ++r) { m_run[qt][r] = -1e30f; l_run[qt][r] = 0.f; }
    f32x4_t Oacc[2][4] = {};
    int kv0 = n * 128 - 128;
    int lo = (n == 0) ? 2 : 0;
    int hi = (n == 31) ? 4 : 6;
    int tbase = l15 + 127 - w * 32 - quad * 4;   // bias-table base (per-thread, hoisted)
    // K/V register staging (T14): kr/vr hold next chunk, loaded during previous compute
    int krow = tid >> 3, kcol = (tid & 7) * 8;
    int vkey = tid >> 2, vc0 = (tid & 3) * 16;
    uint4 kr0, kr1;
    union { uint4 u[2]; bf16 hh[16]; } vr;
    auto loadKV = [&](int kst) {
        const bf16* kg = k + (size_t)(b * 4096 + kst + krow) * 512 + h * 64 + kcol;
        kr0 = *(const uint4*)kg;
        kr1 = *(const uint4*)(kg + (size_t)32 * 512);
        const bf16* vg = v + (size_t)(b * 4096 + kst + vkey) * 512 + h * 64 + vc0;
        vr.u[0] = *(const uint4*)vg;
        vr.u[1] = *(const uint4*)(vg + 8);
    };
    loadKV(kv0 + lo * 64);
    for (int ch = lo; ch < hi; ++ch) {
        __syncthreads();                         // prev chunk's MFMA reads of Ks/Vt done
        *(uint4*)&Ks[krow][kcol] = kr0;
        *(uint4*)&Ks[krow + 32][kcol] = kr1;
#pragma unroll
        for (int j = 0; j < 16; ++j) Vt[vc0 + j][vkey] = vr.hh[j];
        if (ch + 1 < hi) loadKV(kv0 + (ch + 1) * 64);   // prefetch: lands during compute
        __syncthreads();
        float sc[2][4][4];
        __builtin_amdgcn_s_setprio(1);
#pragma unroll
        for (int qt = 0; qt < 2; ++qt)
#pragma unroll
            for (int nt = 0; nt < 4; ++nt) {
                f32x4_t a = {};
#pragma unroll
                for (int ks = 0; ks < 2; ++ks) {
                    bf16x8_t kf = *(const bf16x8_t*)&Ks[nt * 16 + l15][ks * 32 + quad * 8];
                    a = __builtin_amdgcn_mfma_f32_16x16x32_bf16(qf[qt][ks], kf, a, 0, 0, 0);
                }
#pragma unroll
                for (int r = 0; r < 4; ++r) sc[qt][nt][r] = a[r];
            }
        __builtin_amdgcn_s_setprio(0);
        // bias + mask via padded table: one LDS read + one add per element
        {
            int tb0 = tbase + ch * 64;
#pragma unroll
            for (int qt = 0; qt < 2; ++qt)
#pragma unroll
                for (int nt = 0; nt < 4; ++nt)
#pragma unroll
                    for (int r = 0; r < 4; ++r)
                        sc[qt][nt][r] += relb2[tb0 + nt * 16 - qt * 16 - r];
        }
        // row max + defer-max decision (THR=8, wave-uniform)
        float mx[2][4];
        int need = 0;
#pragma unroll
        for (int qt = 0; qt < 2; ++qt)
#pragma unroll
            for (int r = 0; r < 4; ++r) {
                float m3 = fmaxf(fmaxf(sc[qt][0][r], sc[qt][1][r]), fmaxf(sc[qt][2][r], sc[qt][3][r]));
#pragma unroll
                for (int mk = 1; mk <= 8; mk <<= 1) m3 = fmaxf(m3, __shfl_xor(m3, mk, 64));
                mx[qt][r] = m3;
                need |= (m3 > m_run[qt][r] + 8.f) ? 1 : 0;
            }
        bool slow = __any(need);
        float al[2][4];
#pragma unroll
        for (int qt = 0; qt < 2; ++qt)
#pragma unroll
            for (int r = 0; r < 4; ++r) {
                float mn = slow ? fmaxf(m_run[qt][r], mx[qt][r]) : m_run[qt][r];
                float ps = 0.f;
#pragma unroll
                for (int nt = 0; nt < 4; ++nt) {
                    float p = __expf(sc[qt][nt][r] - mn);
                    sc[qt][nt][r] = p;
                    ps += p;
                }
#pragma unroll
                for (int mk = 1; mk <= 8; mk <<= 1) ps += __shfl_xor(ps, mk, 64);
                if (slow) {
                    float a = __expf(m_run[qt][r] - mn);
                    l_run[qt][r] = l_run[qt][r] * a + ps;
                    m_run[qt][r] = mn;
                    al[qt][r] = a;
                } else {
                    l_run[qt][r] += ps;
                }
            }
        // P -> LDS (wave-local buffer; same-wave read below needs no barrier)
#pragma unroll
        for (int qt = 0; qt < 2; ++qt)
#pragma unroll
            for (int nt = 0; nt < 4; ++nt)
#pragma unroll
                for (int r = 0; r < 4; ++r)
                    Pb[w][qt * 16 + quad * 4 + r][nt * 16 + l15] = f2bf(sc[qt][nt][r]);
#pragma unroll
        for (int qt = 0; qt < 2; ++qt) {
            if (slow) {
#pragma unroll
                for (int dt = 0; dt < 4; ++dt)
#pragma unroll
                    for (int r = 0; r < 4; ++r)
                        Oacc[qt][dt][r] *= al[qt][r];
            }
            bf16x8_t pf[2];
#pragma unroll
            for (int ks = 0; ks < 2; ++ks)
                pf[ks] = *(const bf16x8_t*)&Pb[w][qt * 16 + l15][ks * 32 + quad * 8];
            __builtin_amdgcn_s_setprio(1);
#pragma unroll
            for (int dt = 0; dt < 4; ++dt) {
                f32x4_t a = Oacc[qt][dt];
#pragma unroll
                for (int ks = 0; ks < 2; ++ks) {
                    bf16x8_t vf = *(const bf16x8_t*)&Vt[dt * 16 + l15][ks * 32 + quad * 8];
                    a = __builtin_amdgcn_mfma_f32_16x16x32_bf16(pf[ks], vf, a, 0, 0, 0);
                }
                Oacc[qt][dt] = a;
            }
            __builtin_amdgcn_s_setprio(0);
        }
    }
#pragma unroll
    for (int qt = 0; qt < 2; ++qt)
#pragma unroll
        for (int r = 0; r < 4; ++r) {
            float inv = 1.f / l_run[qt][r];
            int row = n * 128 + w * 32 + qt * 16 + quad * 4 + r;
#pragma unroll
            for (int dt = 0; dt < 4; ++dt)
                out[(size_t)(b * 4096 + row) * 512 + h * 64 + dt * 16 + l15] = f2bf(Oacc[qt][dt][r] * inv);
        }
}

// ---------------- tiled depthwise conv (KS=31) + BN + SiLU ----------------
__global__ __launch_bounds__(256) void k_conv(const bf16* __restrict__ in, const float* __restrict__ w,
                                              const float* __restrict__ wb, const float* __restrict__ bg,
                                              const float* __restrict__ bb2, const float* __restrict__ bm,
                                              const float* __restrict__ bvv, bf16* __restrict__ out) {
    __shared__ float wl[64 * 31];
    int d0 = blockIdx.x * 64, s0 = blockIdx.y * 64, b = blockIdx.z;
    for (int i = threadIdx.x; i < 64 * 31; i += 256) wl[i] = w[d0 * 31 + i];
    __syncthreads();
    int dl = threadIdx.x & 63, chunk = threadIdx.x >> 6;
    int d = d0 + dl;
    int s00 = s0 + chunk * 16;
    float wr[31];
#pragma unroll
    for (int t = 0; t < 31; ++t) wr[t] = wl[dl * 31 + t];
    float xw[46];
    const bf16* base = in + (size_t)(b * 4096) * 512 + d;
#pragma unroll
    for (int i = 0; i < 46; ++i) {
        int s = s00 - 15 + i;
        xw[i] = (s >= 0 && s < 4096) ? bf2f(base[(size_t)s * 512]) : 0.f;
    }
    float scv = bg[d] * rsqrtf(bvv[d] + 1e-5f);
    float wbd = wb[d], bmd = bm[d], bbd = bb2[d];
    bf16* op = out + (size_t)(b * 4096 + s00) * 512 + d;
#pragma unroll
    for (int j = 0; j < 16; ++j) {
        float acc = 0.f;
#pragma unroll
        for (int t = 0; t < 31; ++t) acc += wr[t] * xw[j + t];
        acc += wbd;
        acc = (acc - bmd) * scv + bbd;
        acc = acc / (1.f + __expf(-acc));
        op[(size_t)j * 512] = f2bf(acc);
    }
}

extern "C" void kernel_launch(void* const* d_in, const int* in_sizes, int n_in,
                              void* d_out, int out_size, void* d_ws, size_t ws_size,
                              hipStream_t stream) {
    (void)in_sizes; (void)n_in; (void)out_size; (void)ws_size;
    const float* x = (const float*)d_in[0];
    char* ws = (char*)d_ws;
    float* xf   = (float*)ws;                      // [0,32M)   fp32 residual
    bf16* ln_bf = (bf16*)(ws + 33554432);          // [32M,48M) LN output (bf16)
    bf16* h_bf  = (bf16*)(ws + 50331648);          // [48M,112M) hidden / q,k,v
    bf16* g_bf  = (bf16*)(ws + 117440512);         // [112M,128M) GLU out
    bf16* t_bf  = (bf16*)(ws + 134217728);         // [128M,144M) attn/conv out
    bf16* wc    = (bf16*)(ws + 150994944);         // [144M,...) converted bf16 weights
    bf16 *qb = h_bf;
    bf16* w_f11 = wc;                // [2048][512]
    bf16* w_f12 = wc + 1048576;      // [512][2048]
    bf16* w_f21 = wc + 2097152;      // [2048][512]
    bf16* w_f22 = wc + 3145728;      // [512][2048]
    bf16* w_q   = wc + 4194304;      // [1536][512] fused qkv (contiguous)
    bf16* w_o   = wc + 4980736;      // [512][512]
    bf16* w_p1  = wc + 5242880;      // [1024][512] interleaved a/gate rows
    bf16* w_p2  = wc + 5767168;      // [512][512]

    // fused weight conversion (10 matrices, one launch)
    WSrcs srcs;
    srcs.s[0] = (const float*)d_in[3];  srcs.s[1] = (const float*)d_in[5];
    srcs.s[2] = (const float*)d_in[9];  srcs.s[3] = (const float*)d_in[11];
    srcs.s[4] = (const float*)d_in[15]; srcs.s[5] = (const float*)d_in[16];
    srcs.s[6] = (const float*)d_in[17]; srcs.s[7] = (const float*)d_in[18];
    srcs.s[8] = (const float*)d_in[26]; srcs.s[9] = (const float*)d_in[34];
    k_wconv<<<5888, 256, 0, stream>>>(srcs, wc);

    // FFN1: xf = x + 0.5*FFN(LN(x))
    k_ln<true><<<4096, 256, 0, stream>>>(x, (const float*)d_in[1], (const float*)d_in[2], ln_bf);
    k_gemm<1, 128><<<2048, 256, 0, stream>>>(ln_bf, w_f11, (const float*)d_in[4], h_bf, 16384, 2048, 512, 0.f, nullptr, nullptr, nullptr, 16);
    k_gemm<2, 128><<<512, 256, 0, stream>>>(h_bf, w_f12, (const float*)d_in[6], xf, 16384, 512, 2048, 0.5f, nullptr, nullptr, x, 4);
    // attention (fused QKV)
    k_ln<true><<<4096, 256, 0, stream>>>(xf, (const float*)d_in[13], (const float*)d_in[14], ln_bf);
    k_gemm<3, 128><<<1536, 256, 0, stream>>>(ln_bf, w_q, (const float*)d_in[19], qb, 16384, 1536, 512, 0.f,
                                             (const float*)d_in[20], (const float*)d_in[21], nullptr, 12);
    k_attn<<<1024, 256, 0, stream>>>(qb, qb + 8388608, qb + 16777216, (const float*)d_in[23], t_bf);
    k_gemm<2, 128><<<512, 256, 0, stream>>>(t_bf, w_o, (const float*)d_in[22], xf, 16384, 512, 512, 1.0f, nullptr, nullptr, xf, 4);
    // conv module (pw1 + fused GLU)
    k_ln<true><<<4096, 256, 0, stream>>>(xf, (const float*)d_in[24], (const float*)d_in[25], ln_bf);
    k_gemm<5, 128><<<1024, 256, 0, stream>>>(ln_bf, w_p1, (const float*)d_in[27], g_bf, 16384, 1024, 512, 0.f, nullptr, nullptr, nullptr, 8);
    k_conv<<<dim3(8, 64, 4), 256, 0, stream>>>(g_bf, (const float*)d_in[28], (const float*)d_in[29], (const float*)d_in[30],
                                               (const float*)d_in[31], (const float*)d_in[32], (const float*)d_in[33], t_bf);
    k_gemm<2, 128><<<512, 256, 0, stream>>>(t_bf, w_p2, (const float*)d_in[35], xf, 16384, 512, 512, 1.0f, nullptr, nullptr, xf, 4);
    // FFN2
    k_ln<true><<<4096, 256, 0, stream>>>(xf, (const float*)d_in[7], (const float*)d_in[8], ln_bf);
    k_gemm<1, 128><<<2048, 256, 0, stream>>>(ln_bf, w_f21, (const float*)d_in[10], h_bf, 16384, 2048, 512, 0.f, nullptr, nullptr, nullptr, 16);
    k_gemm<2, 128><<<512, 256, 0, stream>>>(h_bf, w_f22, (const float*)d_in[12], xf, 16384, 512, 2048, 0.5f, nullptr, nullptr, xf, 4);
    // final LN -> fp32 out
    k_ln<false><<<4096, 256, 0, stream>>>(xf, (const float*)d_in[36], (const float*)d_in[37], d_out);
}